// Round 6
// baseline (356.531 us; speedup 1.0000x reference)
//
#include <hip/hip_runtime.h>
#include <cstddef>

#define TSEQ 2048
#define NB   2
#define DM   1024          // D_MODEL == DI
#define DST  16            // D_STATE
#define ROWS (NB*TSEQ)     // 4096
#define GCH  32            // scan chunks
#define LCH  64            // chunk length
#define NDTBC 1152         // dt(1024) + B(16) + C(16) + pad(96)

typedef float  f32x4  __attribute__((ext_vector_type(4)));
typedef short  bf16x8 __attribute__((ext_vector_type(8)));
typedef unsigned short us4 __attribute__((ext_vector_type(4)));
typedef unsigned short u16;

// ---------------- helpers ----------------
__device__ __forceinline__ float u2f(unsigned short u) {
  return __uint_as_float(((unsigned)u) << 16);
}
__device__ __forceinline__ unsigned short bf16_rn(float x) {
  unsigned u = __float_as_uint(x);
  u += 0x7fff + ((u >> 16) & 1);
  return (unsigned short)(u >> 16);
}
__device__ __forceinline__ void split1(float x, u16& h, u16& l) {
  h = bf16_rn(x);
  l = bf16_rn(x - u2f(h));
}
__device__ __forceinline__ void split4(const float4& v, us4& h, us4& l) {
  u16 h0, h1, h2, h3, l0, l1, l2, l3;
  split1(v.x, h0, l0); split1(v.y, h1, l1);
  split1(v.z, h2, l2); split1(v.w, h3, l3);
  h = (us4){h0, h1, h2, h3};
  l = (us4){l0, l1, l2, l3};
}
__device__ __forceinline__ float softplus_f(float x) {
  return fmaxf(x, 0.0f) + log1pf(expf(-fabsf(x)));
}
__device__ __forceinline__ float silu_f(float x) {
  return x / (1.0f + expf(-x));
}
__device__ __forceinline__ void async16(const void* g, void* l) {
  __builtin_amdgcn_global_load_lds(
      (const __attribute__((address_space(1))) unsigned int*)g,
      (__attribute__((address_space(3))) unsigned int*)l, 16, 0, 0);
}
__device__ __forceinline__ float block_reduce_sum(float v, float* smem) {
#pragma unroll
  for (int off = 32; off > 0; off >>= 1) v += __shfl_down(v, off);
  int wid = threadIdx.x >> 6, lane = threadIdx.x & 63;
  if (lane == 0) smem[wid] = v;
  __syncthreads();
  float r = (smem[0] + smem[1]) + (smem[2] + smem[3]);
  __syncthreads();
  return r;
}

// ---------------- weight transpose + bf16 split: W[K][N] -> T[N][K] hi/lo ----------------
__global__ __launch_bounds__(256) void wsplit_t(const float* __restrict__ W,
    u16* __restrict__ Th, u16* __restrict__ Tl, int K, int N) {
  __shared__ float t[32][33];
  int k0 = blockIdx.y * 32, n0 = blockIdx.x * 32;
  int r = threadIdx.x >> 3, cq = (threadIdx.x & 7) * 4;
  float4 v = *(const float4*)&W[(size_t)(k0 + r) * N + n0 + cq];
  t[r][cq + 0] = v.x; t[r][cq + 1] = v.y; t[r][cq + 2] = v.z; t[r][cq + 3] = v.w;
  __syncthreads();
  int n = threadIdx.x >> 3, kq = (threadIdx.x & 7) * 4;
  float4 w4;
  w4.x = t[kq + 0][n]; w4.y = t[kq + 1][n]; w4.z = t[kq + 2][n]; w4.w = t[kq + 3][n];
  us4 h, l;
  split4(w4, h, l);
  size_t o = (size_t)(n0 + n) * K + k0 + kq;
  *(us4*)&Th[o] = h;
  *(us4*)&Tl[o] = l;
}

// ---------------- B/C weight rows (1024..1151) of the combined dt|B|C matrix ----------------
__global__ __launch_bounds__(256) void bc_prep(const float* __restrict__ Bw,
    const float* __restrict__ Cw, u16* __restrict__ Th, u16* __restrict__ Tl) {
  int n = DM + blockIdx.x;          // 1024..1151
  int k = threadIdx.x * 4;
  float4 v = {0.f, 0.f, 0.f, 0.f};
  if (n < DM + DST) {
    int s = n - DM;
    v.x = Bw[(k + 0) * DST + s]; v.y = Bw[(k + 1) * DST + s];
    v.z = Bw[(k + 2) * DST + s]; v.w = Bw[(k + 3) * DST + s];
  } else if (n < DM + 2 * DST) {
    int s = n - DM - DST;
    v.x = Cw[(k + 0) * DST + s]; v.y = Cw[(k + 1) * DST + s];
    v.z = Cw[(k + 2) * DST + s]; v.w = Cw[(k + 3) * DST + s];
  }
  us4 h, l;
  split4(v, h, l);
  size_t o = (size_t)n * DM + k;
  *(us4*)&Th[o] = h;
  *(us4*)&Tl[o] = l;
}

// ---------------- LayerNorm -> bf16 hi/lo ----------------
__global__ __launch_bounds__(256) void ln_kernel(const float* __restrict__ x,
    const float* __restrict__ g, const float* __restrict__ b,
    u16* __restrict__ xh, u16* __restrict__ xl) {
  __shared__ float smem[4];
  int r = blockIdx.x;
  size_t base = (size_t)r * DM + threadIdx.x * 4;
  float4 x4 = *(const float4*)&x[base];
  float s = block_reduce_sum(x4.x + x4.y + x4.z + x4.w, smem);
  float mu = s * (1.0f / DM);
  float d0 = x4.x - mu, d1 = x4.y - mu, d2 = x4.z - mu, d3 = x4.w - mu;
  float v = block_reduce_sum(d0*d0 + d1*d1 + d2*d2 + d3*d3, smem) * (1.0f / DM);
  float inv = rsqrtf(v + 1e-5f);
  float4 g4 = *(const float4*)&g[threadIdx.x * 4];
  float4 b4 = *(const float4*)&b[threadIdx.x * 4];
  float4 o;
  o.x = d0 * inv * g4.x + b4.x;
  o.y = d1 * inv * g4.y + b4.y;
  o.z = d2 * inv * g4.z + b4.z;
  o.w = d3 * inv * g4.w + b4.w;
  us4 h, l;
  split4(o, h, l);
  *(us4*)&xh[base] = h;
  *(us4*)&xl[base] = l;
}

// ---------------- MFMA GEMM (bf16x3 split, BM=128 BN=128 BK=32, double-buffered LDS) ----------------
// A as hi/lo bf16 [M][K]; B as transposed hi/lo bf16 [N][K]. Wave tile 64x64 (4x4 of 16x16).
// EPI 2: resid + acc; EPI 3: split cols into C (n<DM) / C2 (n>=DM)
// EPI 4: col<DM -> softplus(acc+bias[col]); DM<=col<DM+16 -> C2 (Bm); next 16 -> C3 (Cm); else discard
#define LBUF 16384   // u16 per buffer: Ah 4096 | Al 4096 | Bh 4096 | Bl 4096
template <int EPI>
__global__ __launch_bounds__(256) void gemm_mfma(
    const u16* __restrict__ Ah, const u16* __restrict__ Al,
    const u16* __restrict__ Bh, const u16* __restrict__ Bl,
    float* __restrict__ C, int M, int N, int Kd,
    const float* __restrict__ bias, const float* __restrict__ resid,
    float* __restrict__ C2, float* __restrict__ C3) {
  __shared__ __align__(16) u16 lds[2 * LBUF];
  int tid = threadIdx.x, wave = tid >> 6, lane = tid & 63;
  int m0 = blockIdx.y * 128, n0 = blockIdx.x * 128;
  int wm = (wave >> 1) * 64, wn = (wave & 1) * 64;

  // staging: 2048 16B-chunks per buffer, 8 rounds x 256 threads
  // layout per buffer: Ah[128][32] | Al[128][32] | Bh[128][32] | Bl[128][32]
  const u16* gptr[8];
  int ldst[8];
#pragma unroll
  for (int r = 0; r < 8; ++r) {
    int c = r * 256 + tid;
    int kq = c & 3;
    const u16* base;
    int row;
    if (c < 512)        { base = Ah + (size_t)m0 * Kd; row = c >> 2; }
    else if (c < 1024)  { base = Al + (size_t)m0 * Kd; row = (c - 512) >> 2; }
    else if (c < 1536)  { base = Bh + (size_t)n0 * Kd; row = (c - 1024) >> 2; }
    else                { base = Bl + (size_t)n0 * Kd; row = (c - 1536) >> 2; }
    gptr[r] = base + (size_t)row * Kd + kq * 8;
    ldst[r] = c * 8;
  }

  f32x4 acc[4][4];
#pragma unroll
  for (int i = 0; i < 4; ++i)
#pragma unroll
    for (int j = 0; j < 4; ++j) acc[i][j] = (f32x4){0.f, 0.f, 0.f, 0.f};
  int fr = lane & 15, quad = lane >> 4;

  // prologue: stage k=0 into buffer 0
#pragma unroll
  for (int r = 0; r < 8; ++r) async16(gptr[r], lds + ldst[r]);

  int nsteps = Kd / 32;
  for (int s = 0; s < nsteps; ++s) {
    int cur = (s & 1) * LBUF;
    __syncthreads();  // drains cur's loads (issued one step ago, overlapped with prev compute)
    if (s + 1 < nsteps) {
      int ko = (s + 1) * 32;
      int nxt = ((s + 1) & 1) * LBUF;
#pragma unroll
      for (int r = 0; r < 8; ++r) async16(gptr[r] + ko, lds + nxt + ldst[r]);
    }
    const u16* sAh = lds + cur;
    const u16* sAl = lds + cur + 4096;
    const u16* sBh = lds + cur + 8192;
    const u16* sBl = lds + cur + 12288;
    bf16x8 afh[4], afl[4], bfh[4], bfl[4];
#pragma unroll
    for (int t = 0; t < 4; ++t) {
      int ro = (wm + t * 16 + fr) * 32 + quad * 8;
      afh[t] = *(const bf16x8*)&sAh[ro];
      afl[t] = *(const bf16x8*)&sAl[ro];
      int co = (wn + t * 16 + fr) * 32 + quad * 8;
      bfh[t] = *(const bf16x8*)&sBh[co];
      bfl[t] = *(const bf16x8*)&sBl[co];
    }
#pragma unroll
    for (int mt = 0; mt < 4; ++mt)
#pragma unroll
      for (int nt = 0; nt < 4; ++nt) {
        acc[mt][nt] = __builtin_amdgcn_mfma_f32_16x16x32_bf16(afh[mt], bfh[nt], acc[mt][nt], 0, 0, 0);
        acc[mt][nt] = __builtin_amdgcn_mfma_f32_16x16x32_bf16(afh[mt], bfl[nt], acc[mt][nt], 0, 0, 0);
        acc[mt][nt] = __builtin_amdgcn_mfma_f32_16x16x32_bf16(afl[mt], bfh[nt], acc[mt][nt], 0, 0, 0);
      }
  }

#pragma unroll
  for (int mt = 0; mt < 4; ++mt)
#pragma unroll
    for (int nt = 0; nt < 4; ++nt) {
      int col = n0 + wn + nt * 16 + fr;
#pragma unroll
      for (int r = 0; r < 4; ++r) {
        int row = m0 + wm + mt * 16 + quad * 4 + r;
        float v = acc[mt][nt][r];
        if (EPI == 2) {
          v += resid[(size_t)row * N + col];
          C[(size_t)row * N + col] = v;
        } else if (EPI == 3) {
          if (col < DM) C[(size_t)row * DM + col] = v;
          else          C2[(size_t)row * DM + col - DM] = v;
        } else if (EPI == 4) {
          if (col < DM) {
            C[(size_t)row * DM + col] = softplus_f(v + bias[col]);
          } else if (col < DM + DST) {
            C2[(size_t)row * DST + col - DM] = v;
          } else if (col < DM + 2 * DST) {
            C3[(size_t)row * DST + col - DM - DST] = v;
          }
        } else {
          C[(size_t)row * N + col] = v;
        }
      }
    }
}

// ---------------- causal depthwise conv (K=4) + SiLU -> xs hi/lo ----------------
__global__ __launch_bounds__(256) void conv_silu_kernel(
    const float* __restrict__ xin, const float* __restrict__ w,
    const float* __restrict__ cb, u16* __restrict__ xsh, u16* __restrict__ xsl) {
  int r = blockIdx.x;
  int b = r >> 11, t = r & 2047;
  int d = threadIdx.x * 4;
  float4 w0 = *(const float4*)&w[(d + 0) * 4];
  float4 w1 = *(const float4*)&w[(d + 1) * 4];
  float4 w2 = *(const float4*)&w[(d + 2) * 4];
  float4 w3 = *(const float4*)&w[(d + 3) * 4];
  float4 s = *(const float4*)&cb[d];
#pragma unroll
  for (int k = 0; k < 4; ++k) {
    int ts = t + k - 3;
    if (ts >= 0) {
      float4 xv = *(const float4*)&xin[((size_t)(b * TSEQ + ts)) * DM + d];
      s.x = fmaf(xv.x, (&w0.x)[k], s.x);
      s.y = fmaf(xv.y, (&w1.x)[k], s.y);
      s.z = fmaf(xv.z, (&w2.x)[k], s.z);
      s.w = fmaf(xv.w, (&w3.x)[k], s.w);
    }
  }
  float4 o;
  o.x = silu_f(s.x); o.y = silu_f(s.y); o.z = silu_f(s.z); o.w = silu_f(s.w);
  us4 h, l;
  split4(o, h, l);
  size_t base = (size_t)r * DM + d;
  *(us4*)&xsh[base] = h;
  *(us4*)&xsl[base] = l;
}

// ---------------- scan phase A ----------------
__global__ __launch_bounds__(256) void scan_a_kernel(
    const float* __restrict__ dt, const u16* __restrict__ xsh,
    const u16* __restrict__ xsl,
    const float* __restrict__ Bm, const float* __restrict__ Cm,
    const float* __restrict__ logA, float* __restrict__ yloc,
    float* __restrict__ cumP, float* __restrict__ hend) {
  int blk = blockIdx.x;
  int dblk = blk & 3, c = (blk >> 2) & 31, b = blk >> 7;
  int di = dblk * 256 + threadIdx.x;
  __shared__ float sB[LCH][DST];
  __shared__ float sC[LCH][DST];
  {
    int tl = threadIdx.x >> 2, sq = (threadIdx.x & 3) * 4;
    size_t base = ((size_t)(b * TSEQ + c * LCH + tl)) * DST + sq;
    *(float4*)&sB[tl][sq] = *(const float4*)&Bm[base];
    *(float4*)&sC[tl][sq] = *(const float4*)&Cm[base];
  }
  __syncthreads();
  float A_di = -expf(logA[di]);
  float h[DST];
#pragma unroll
  for (int s = 0; s < DST; ++s) h[s] = 0.0f;
  float cp = 1.0f;
  for (int tl = 0; tl < LCH; ++tl) {
    size_t idx = ((size_t)(b * TSEQ + c * LCH + tl)) * DM + di;
    float dtv = dt[idx];
    float xv  = u2f(xsh[idx]) + u2f(xsl[idx]);
    float decay = expf(fminf(dtv * A_di, 0.0f));
    float u = dtv * xv;
    float y = 0.0f;
#pragma unroll
    for (int s4 = 0; s4 < 4; ++s4) {
      float4 b4 = *(const float4*)&sB[tl][s4 * 4];
      float4 c4 = *(const float4*)&sC[tl][s4 * 4];
      h[s4*4+0] = fmaf(h[s4*4+0], decay, u * b4.x); y = fmaf(h[s4*4+0], c4.x, y);
      h[s4*4+1] = fmaf(h[s4*4+1], decay, u * b4.y); y = fmaf(h[s4*4+1], c4.y, y);
      h[s4*4+2] = fmaf(h[s4*4+2], decay, u * b4.z); y = fmaf(h[s4*4+2], c4.z, y);
      h[s4*4+3] = fmaf(h[s4*4+3], decay, u * b4.w); y = fmaf(h[s4*4+3], c4.w, y);
    }
    cp *= decay;
    yloc[idx] = y;
    cumP[idx] = cp;
  }
#pragma unroll
  for (int s = 0; s < DST; ++s)
    hend[(((size_t)(b * GCH + c)) * DST + s) * DM + di] = h[s];
}

// ---------------- scan phase B (in place: hend -> Hinit) ----------------
__global__ __launch_bounds__(256) void scan_b_kernel(
    const float* __restrict__ cumP, float* __restrict__ hboth) {
  int blk = blockIdx.x;
  int dblk = blk & 3, s = (blk >> 2) & 15, b = blk >> 6;
  int di = dblk * 256 + threadIdx.x;
  float H = 0.0f;
  for (int c = 0; c < GCH; ++c) {
    size_t hidx = (((size_t)(b * GCH + c)) * DST + s) * DM + di;
    float e = hboth[hidx];
    hboth[hidx] = H;
    float P = cumP[((size_t)(b * TSEQ + c * LCH + LCH - 1)) * DM + di];
    H = e + P * H;
  }
}

// ---------------- scan phase C + D-skip + gate -> y hi/lo ----------------
__global__ __launch_bounds__(256) void scan_c_kernel(
    const float* __restrict__ Cm, const float* __restrict__ Hinit,
    const u16* __restrict__ xsh, const u16* __restrict__ xsl,
    const float* __restrict__ zbuf,
    const float* __restrict__ Dp, const float* __restrict__ cumP,
    const float* __restrict__ yloc, u16* __restrict__ yh, u16* __restrict__ yl) {
  int r = blockIdx.x;
  int b = r >> 11, t = r & 2047, c = t >> 6;
  int di = threadIdx.x * 4;
  size_t idx = (size_t)r * DM + di;
  float4 y4 = *(const float4*)&yloc[idx];
  float4 p4 = *(const float4*)&cumP[idx];
  float4 dot = {0.f, 0.f, 0.f, 0.f};
  size_t hbase = ((size_t)(b * GCH + c)) * DST * DM + di;
#pragma unroll
  for (int s = 0; s < DST; ++s) {
    float cs = Cm[(size_t)r * DST + s];
    float4 h4 = *(const float4*)&Hinit[hbase + (size_t)s * DM];
    dot.x = fmaf(cs, h4.x, dot.x);
    dot.y = fmaf(cs, h4.y, dot.y);
    dot.z = fmaf(cs, h4.z, dot.z);
    dot.w = fmaf(cs, h4.w, dot.w);
  }
  y4.x = fmaf(p4.x, dot.x, y4.x);
  y4.y = fmaf(p4.y, dot.y, y4.y);
  y4.z = fmaf(p4.z, dot.z, y4.z);
  y4.w = fmaf(p4.w, dot.w, y4.w);
  us4 xh4 = *(const us4*)&xsh[idx];
  us4 xl4 = *(const us4*)&xsl[idx];
  float4 D4 = *(const float4*)&Dp[di];
  y4.x = fmaf(u2f(xh4.x) + u2f(xl4.x), D4.x, y4.x);
  y4.y = fmaf(u2f(xh4.y) + u2f(xl4.y), D4.y, y4.y);
  y4.z = fmaf(u2f(xh4.z) + u2f(xl4.z), D4.z, y4.z);
  y4.w = fmaf(u2f(xh4.w) + u2f(xl4.w), D4.w, y4.w);
  float4 z4 = *(const float4*)&zbuf[idx];
  y4.x *= silu_f(z4.x);
  y4.y *= silu_f(z4.y);
  y4.z *= silu_f(z4.z);
  y4.w *= silu_f(z4.w);
  us4 h, l;
  split4(y4, h, l);
  *(us4*)&yh[idx] = h;
  *(us4*)&yl[idx] = l;
}

// ---------------- launch ----------------
extern "C" void kernel_launch(void* const* d_in, const int* in_sizes, int n_in,
                              void* d_out, int out_size, void* d_ws, size_t ws_size,
                              hipStream_t stream) {
  const float* x      = (const float*)d_in[0];
  const float* ln_g   = (const float*)d_in[1];
  const float* ln_b   = (const float*)d_in[2];
  const float* W_in   = (const float*)d_in[3];
  const float* conv_w = (const float*)d_in[4];
  const float* conv_b = (const float*)d_in[5];
  const float* dt_w   = (const float*)d_in[6];
  const float* dt_b   = (const float*)d_in[7];
  const float* B_w    = (const float*)d_in[8];
  const float* C_w    = (const float*)d_in[9];
  const float* log_A  = (const float*)d_in[10];
  const float* D_par  = (const float*)d_in[11];
  const float* W_out  = (const float*)d_in[12];
  float* out = (float*)d_out;

  float* ws = (float*)d_ws;
  const size_t NE = (size_t)ROWS * DM;  // 4M elements
  float* bufX  = ws;             // x_ssm pre-conv; after conv reused for Bm/Cm/hend/woutT
  float* bufZ  = bufX + NE;      // z half
  float* bufP  = bufZ + NE;      // cumP; early: WinT + dt|B|C weights
  float* bufY  = bufP + NE;      // yloc
  u16*   actH  = (u16*)(bufY + NE);   // xn hi -> xs hi
  u16*   actL  = actH + NE;
  float* bufDT = (float*)(actH + 2 * NE);  // dt; later y hi/lo
  u16*   yH    = (u16*)bufDT;
  u16*   yL    = yH + NE;
  // weights (early phase) aliased into bufP (16 MB): 4+4+2.25+2.25 = 12.5 MB
  u16* winTh  = (u16*)bufP;
  u16* winTl  = winTh + (size_t)2 * DM * DM;
  u16* dtbcTh = winTl + (size_t)2 * DM * DM;
  u16* dtbcTl = dtbcTh + (size_t)NDTBC * DM;
  // aliases into bufX (valid after conv)
  float* bufBm = bufX;
  float* bufCm = bufBm + (size_t)ROWS * DST;
  float* bufHe = bufCm + (size_t)ROWS * DST;
  u16* woutTh  = (u16*)(bufHe + (size_t)NB * GCH * DST * DM);
  u16* woutTl  = woutTh + (size_t)DM * DM;

  // 0. weight prep: W_in transpose; combined dt|B|C transpose (rows 0..1023 dt, 1024..1151 B/C/pad)
  wsplit_t<<<dim3(2 * DM / 32, DM / 32), 256, 0, stream>>>(W_in, winTh, winTl, DM, 2 * DM);
  wsplit_t<<<dim3(DM / 32, DM / 32), 256, 0, stream>>>(dt_w, dtbcTh, dtbcTl, DM, DM);
  bc_prep<<<NDTBC - DM, 256, 0, stream>>>(B_w, C_w, dtbcTh, dtbcTl);
  // 1. LayerNorm -> xn hi/lo
  ln_kernel<<<ROWS, 256, 0, stream>>>(x, ln_g, ln_b, actH, actL);
  // 2. xz GEMM, split epilogue -> bufX (x half), bufZ (z half)
  gemm_mfma<3><<<dim3(2 * DM / 128, ROWS / 128), 256, 0, stream>>>(
      actH, actL, winTh, winTl, bufX, ROWS, 2 * DM, DM, nullptr, nullptr, bufZ, nullptr);
  // 3. conv + silu -> xs hi/lo (overwrites xn)
  conv_silu_kernel<<<ROWS, 256, 0, stream>>>(bufX, conv_w, conv_b, actH, actL);
  // 3b. W_out transpose (bufX region now free)
  wsplit_t<<<dim3(DM / 32, DM / 32), 256, 0, stream>>>(W_out, woutTh, woutTl, DM, DM);
  // 4. fused dt+B+C GEMM: softplus(dt)+Bm+Cm in one pass
  gemm_mfma<4><<<dim3(NDTBC / 128, ROWS / 128), 256, 0, stream>>>(
      actH, actL, dtbcTh, dtbcTl, bufDT, ROWS, NDTBC, DM, dt_b, nullptr, bufBm, bufCm);
  // 5-7. chunked scan
  scan_a_kernel<<<NB * GCH * 4, 256, 0, stream>>>(bufDT, actH, actL, bufBm, bufCm,
                                                  log_A, bufY, bufP, bufHe);
  scan_b_kernel<<<NB * DST * 4, 256, 0, stream>>>(bufP, bufHe);
  scan_c_kernel<<<ROWS, 256, 0, stream>>>(bufCm, bufHe, actH, actL, bufZ, D_par,
                                          bufP, bufY, yH, yL);
  // 8. out = x + y @ W_out
  gemm_mfma<2><<<dim3(DM / 128, ROWS / 128), 256, 0, stream>>>(
      yH, yL, woutTh, woutTl, out, ROWS, DM, DM, nullptr, x, nullptr, nullptr);
}

// Round 8
// 350.486 us; speedup vs baseline: 1.0172x; 1.0172x over previous
//
#include <hip/hip_runtime.h>
#include <cstddef>

#define TSEQ 2048
#define NB   2
#define DM   1024          // D_MODEL == DI
#define DST  16            // D_STATE
#define ROWS (NB*TSEQ)     // 4096
#define GCH  32            // scan chunks
#define LCH  64            // chunk length
#define NDTBC 1152         // dt(1024) + B(16) + C(16) + pad(96)

typedef float  f32x4  __attribute__((ext_vector_type(4)));
typedef short  bf16x8 __attribute__((ext_vector_type(8)));
typedef unsigned short us4 __attribute__((ext_vector_type(4)));
typedef unsigned short u16;

// ---------------- helpers ----------------
__device__ __forceinline__ float u2f(unsigned short u) {
  return __uint_as_float(((unsigned)u) << 16);
}
__device__ __forceinline__ unsigned short bf16_rn(float x) {
  unsigned u = __float_as_uint(x);
  u += 0x7fff + ((u >> 16) & 1);
  return (unsigned short)(u >> 16);
}
__device__ __forceinline__ void split1(float x, u16& h, u16& l) {
  h = bf16_rn(x);
  l = bf16_rn(x - u2f(h));
}
__device__ __forceinline__ void split4(const float4& v, us4& h, us4& l) {
  u16 h0, h1, h2, h3, l0, l1, l2, l3;
  split1(v.x, h0, l0); split1(v.y, h1, l1);
  split1(v.z, h2, l2); split1(v.w, h3, l3);
  h = (us4){h0, h1, h2, h3};
  l = (us4){l0, l1, l2, l3};
}
__device__ __forceinline__ float softplus_f(float x) {
  return fmaxf(x, 0.0f) + log1pf(expf(-fabsf(x)));
}
__device__ __forceinline__ float silu_f(float x) {
  return x / (1.0f + expf(-x));
}
__device__ __forceinline__ void async16(const void* g, void* l) {
  __builtin_amdgcn_global_load_lds(
      (const __attribute__((address_space(1))) unsigned int*)g,
      (__attribute__((address_space(3))) unsigned int*)l, 16, 0, 0);
}
__device__ __forceinline__ float block_reduce_sum(float v, float* smem) {
#pragma unroll
  for (int off = 32; off > 0; off >>= 1) v += __shfl_down(v, off);
  int wid = threadIdx.x >> 6, lane = threadIdx.x & 63;
  if (lane == 0) smem[wid] = v;
  __syncthreads();
  float r = (smem[0] + smem[1]) + (smem[2] + smem[3]);
  __syncthreads();
  return r;
}

// ---------------- weight transpose + bf16 split: W[K][N] -> T[N][K] hi/lo ----------------
__global__ __launch_bounds__(256) void wsplit_t(const float* __restrict__ W,
    u16* __restrict__ Th, u16* __restrict__ Tl, int K, int N) {
  __shared__ float t[32][33];
  int k0 = blockIdx.y * 32, n0 = blockIdx.x * 32;
  int r = threadIdx.x >> 3, cq = (threadIdx.x & 7) * 4;
  float4 v = *(const float4*)&W[(size_t)(k0 + r) * N + n0 + cq];
  t[r][cq + 0] = v.x; t[r][cq + 1] = v.y; t[r][cq + 2] = v.z; t[r][cq + 3] = v.w;
  __syncthreads();
  int n = threadIdx.x >> 3, kq = (threadIdx.x & 7) * 4;
  float4 w4;
  w4.x = t[kq + 0][n]; w4.y = t[kq + 1][n]; w4.z = t[kq + 2][n]; w4.w = t[kq + 3][n];
  us4 h, l;
  split4(w4, h, l);
  size_t o = (size_t)(n0 + n) * K + k0 + kq;
  *(us4*)&Th[o] = h;
  *(us4*)&Tl[o] = l;
}

// ---------------- B/C weight rows (1024..1151) of the combined dt|B|C matrix ----------------
__global__ __launch_bounds__(256) void bc_prep(const float* __restrict__ Bw,
    const float* __restrict__ Cw, u16* __restrict__ Th, u16* __restrict__ Tl) {
  int n = DM + blockIdx.x;          // 1024..1151
  int k = threadIdx.x * 4;
  float4 v = {0.f, 0.f, 0.f, 0.f};
  if (n < DM + DST) {
    int s = n - DM;
    v.x = Bw[(k + 0) * DST + s]; v.y = Bw[(k + 1) * DST + s];
    v.z = Bw[(k + 2) * DST + s]; v.w = Bw[(k + 3) * DST + s];
  } else if (n < DM + 2 * DST) {
    int s = n - DM - DST;
    v.x = Cw[(k + 0) * DST + s]; v.y = Cw[(k + 1) * DST + s];
    v.z = Cw[(k + 2) * DST + s]; v.w = Cw[(k + 3) * DST + s];
  }
  us4 h, l;
  split4(v, h, l);
  size_t o = (size_t)n * DM + k;
  *(us4*)&Th[o] = h;
  *(us4*)&Tl[o] = l;
}

// ---------------- LayerNorm -> bf16 hi/lo ----------------
__global__ __launch_bounds__(256) void ln_kernel(const float* __restrict__ x,
    const float* __restrict__ g, const float* __restrict__ b,
    u16* __restrict__ xh, u16* __restrict__ xl) {
  __shared__ float smem[4];
  int r = blockIdx.x;
  size_t base = (size_t)r * DM + threadIdx.x * 4;
  float4 x4 = *(const float4*)&x[base];
  float s = block_reduce_sum(x4.x + x4.y + x4.z + x4.w, smem);
  float mu = s * (1.0f / DM);
  float d0 = x4.x - mu, d1 = x4.y - mu, d2 = x4.z - mu, d3 = x4.w - mu;
  float v = block_reduce_sum(d0*d0 + d1*d1 + d2*d2 + d3*d3, smem) * (1.0f / DM);
  float inv = rsqrtf(v + 1e-5f);
  float4 g4 = *(const float4*)&g[threadIdx.x * 4];
  float4 b4 = *(const float4*)&b[threadIdx.x * 4];
  float4 o;
  o.x = d0 * inv * g4.x + b4.x;
  o.y = d1 * inv * g4.y + b4.y;
  o.z = d2 * inv * g4.z + b4.z;
  o.w = d3 * inv * g4.w + b4.w;
  us4 h, l;
  split4(o, h, l);
  *(us4*)&xh[base] = h;
  *(us4*)&xl[base] = l;
}

// ---------------- MFMA GEMM (bf16x3 split, BM=128 BN=64 BK=32, double-buffered LDS) ----------------
// R5-proven config: wave tile 64x32, 3 blocks/CU. Do not grow the tile (R4/R6 regressed).
// EPI 2: resid + acc; EPI 3: split cols into C (n<DM) / C2 (n>=DM)
// EPI 4: col<DM -> softplus(acc+bias[col]); DM<=col<DM+16 -> C2 (Bm); next 16 -> C3 (Cm); else discard
#define LBUF 12288   // u16 per buffer: Ah 4096 | Al 4096 | Bh 2048 | Bl 2048
template <int EPI>
__global__ __launch_bounds__(256) void gemm_mfma(
    const u16* __restrict__ Ah, const u16* __restrict__ Al,
    const u16* __restrict__ Bh, const u16* __restrict__ Bl,
    float* __restrict__ C, int M, int N, int Kd,
    const float* __restrict__ bias, const float* __restrict__ resid,
    float* __restrict__ C2, float* __restrict__ C3) {
  __shared__ __align__(16) u16 lds[2 * LBUF];
  int tid = threadIdx.x, wave = tid >> 6, lane = tid & 63;
  int m0 = blockIdx.y * 128, n0 = blockIdx.x * 64;
  int wm = (wave >> 1) * 64, wn = (wave & 1) * 32;

  // staging: 1536 16B-chunks per buffer, 6 rounds x 256 threads
  const u16* gptr[6];
  int ldst[6];
#pragma unroll
  for (int r = 0; r < 6; ++r) {
    int c = r * 256 + tid;
    int kq = c & 3;
    const u16* base;
    int row;
    if (c < 512)       { base = Ah + (size_t)m0 * Kd; row = c >> 2; }
    else if (c < 1024) { base = Al + (size_t)m0 * Kd; row = (c - 512) >> 2; }
    else if (c < 1280) { base = Bh + (size_t)n0 * Kd; row = (c - 1024) >> 2; }
    else               { base = Bl + (size_t)n0 * Kd; row = (c - 1280) >> 2; }
    gptr[r] = base + (size_t)row * Kd + kq * 8;
    ldst[r] = c * 8;
  }

  f32x4 acc[4][2];
#pragma unroll
  for (int i = 0; i < 4; ++i)
#pragma unroll
    for (int j = 0; j < 2; ++j) acc[i][j] = (f32x4){0.f, 0.f, 0.f, 0.f};
  int fr = lane & 15, quad = lane >> 4;

  // prologue: stage k=0 into buffer 0
#pragma unroll
  for (int r = 0; r < 6; ++r) async16(gptr[r], lds + ldst[r]);

  int nsteps = Kd / 32;
  for (int s = 0; s < nsteps; ++s) {
    int cur = (s & 1) * LBUF;
    __syncthreads();  // drains cur's loads; all waves done computing the other buffer
    if (s + 1 < nsteps) {
      int ko = (s + 1) * 32;
      int nxt = ((s + 1) & 1) * LBUF;
#pragma unroll
      for (int r = 0; r < 6; ++r) async16(gptr[r] + ko, lds + nxt + ldst[r]);
    }
    const u16* sAh = lds + cur;
    const u16* sAl = lds + cur + 4096;
    const u16* sBh = lds + cur + 8192;
    const u16* sBl = lds + cur + 10240;
    bf16x8 afh[4], afl[4], bfh[2], bfl[2];
#pragma unroll
    for (int t = 0; t < 4; ++t) {
      int ro = (wm + t * 16 + fr) * 32 + quad * 8;
      afh[t] = *(const bf16x8*)&sAh[ro];
      afl[t] = *(const bf16x8*)&sAl[ro];
    }
#pragma unroll
    for (int t = 0; t < 2; ++t) {
      int co = (wn + t * 16 + fr) * 32 + quad * 8;
      bfh[t] = *(const bf16x8*)&sBh[co];
      bfl[t] = *(const bf16x8*)&sBl[co];
    }
#pragma unroll
    for (int mt = 0; mt < 4; ++mt)
#pragma unroll
      for (int nt = 0; nt < 2; ++nt) {
        acc[mt][nt] = __builtin_amdgcn_mfma_f32_16x16x32_bf16(afh[mt], bfh[nt], acc[mt][nt], 0, 0, 0);
        acc[mt][nt] = __builtin_amdgcn_mfma_f32_16x16x32_bf16(afh[mt], bfl[nt], acc[mt][nt], 0, 0, 0);
        acc[mt][nt] = __builtin_amdgcn_mfma_f32_16x16x32_bf16(afl[mt], bfh[nt], acc[mt][nt], 0, 0, 0);
      }
  }

#pragma unroll
  for (int mt = 0; mt < 4; ++mt)
#pragma unroll
    for (int nt = 0; nt < 2; ++nt) {
      int col = n0 + wn + nt * 16 + fr;
#pragma unroll
      for (int r = 0; r < 4; ++r) {
        int row = m0 + wm + mt * 16 + quad * 4 + r;
        float v = acc[mt][nt][r];
        if (EPI == 2) {
          v += resid[(size_t)row * N + col];
          C[(size_t)row * N + col] = v;
        } else if (EPI == 3) {
          if (col < DM) C[(size_t)row * DM + col] = v;
          else          C2[(size_t)row * DM + col - DM] = v;
        } else if (EPI == 4) {
          if (col < DM) {
            C[(size_t)row * DM + col] = softplus_f(v + bias[col]);
          } else if (col < DM + DST) {
            C2[(size_t)row * DST + col - DM] = v;
          } else if (col < DM + 2 * DST) {
            C3[(size_t)row * DST + col - DM - DST] = v;
          }
        } else {
          C[(size_t)row * N + col] = v;
        }
      }
    }
}

// ---------------- causal depthwise conv (K=4) + SiLU -> xs hi/lo ----------------
__global__ __launch_bounds__(256) void conv_silu_kernel(
    const float* __restrict__ xin, const float* __restrict__ w,
    const float* __restrict__ cb, u16* __restrict__ xsh, u16* __restrict__ xsl) {
  int r = blockIdx.x;
  int b = r >> 11, t = r & 2047;
  int d = threadIdx.x * 4;
  float4 w0 = *(const float4*)&w[(d + 0) * 4];
  float4 w1 = *(const float4*)&w[(d + 1) * 4];
  float4 w2 = *(const float4*)&w[(d + 2) * 4];
  float4 w3 = *(const float4*)&w[(d + 3) * 4];
  float4 s = *(const float4*)&cb[d];
#pragma unroll
  for (int k = 0; k < 4; ++k) {
    int ts = t + k - 3;
    if (ts >= 0) {
      float4 xv = *(const float4*)&xin[((size_t)(b * TSEQ + ts)) * DM + d];
      s.x = fmaf(xv.x, (&w0.x)[k], s.x);
      s.y = fmaf(xv.y, (&w1.x)[k], s.y);
      s.z = fmaf(xv.z, (&w2.x)[k], s.z);
      s.w = fmaf(xv.w, (&w3.x)[k], s.w);
    }
  }
  float4 o;
  o.x = silu_f(s.x); o.y = silu_f(s.y); o.z = silu_f(s.z); o.w = silu_f(s.w);
  us4 h, l;
  split4(o, h, l);
  size_t base = (size_t)r * DM + d;
  *(us4*)&xsh[base] = h;
  *(us4*)&xsl[base] = l;
}

// ---------------- scan pass 1: chunk-end state + chunk decay product only ----------------
__global__ __launch_bounds__(256) void scan_pass1(
    const float* __restrict__ dt, const u16* __restrict__ xsh,
    const u16* __restrict__ xsl, const float* __restrict__ Bm,
    const float* __restrict__ logA,
    float* __restrict__ hend, float* __restrict__ pend) {
  int blk = blockIdx.x;
  int dblk = blk & 3, c = (blk >> 2) & 31, b = blk >> 7;
  int di = dblk * 256 + threadIdx.x;
  __shared__ float sB[LCH][DST];
  {
    int tl = threadIdx.x >> 2, sq = (threadIdx.x & 3) * 4;
    size_t base = ((size_t)(b * TSEQ + c * LCH + tl)) * DST + sq;
    *(float4*)&sB[tl][sq] = *(const float4*)&Bm[base];
  }
  __syncthreads();
  float A_di = -expf(logA[di]);
  float h[DST];
#pragma unroll
  for (int s = 0; s < DST; ++s) h[s] = 0.0f;
  float cp = 1.0f;
  for (int tl = 0; tl < LCH; ++tl) {
    size_t idx = ((size_t)(b * TSEQ + c * LCH + tl)) * DM + di;
    float dtv = dt[idx];
    float xv  = u2f(xsh[idx]) + u2f(xsl[idx]);
    float decay = expf(fminf(dtv * A_di, 0.0f));
    float u = dtv * xv;
#pragma unroll
    for (int s4 = 0; s4 < 4; ++s4) {
      float4 b4 = *(const float4*)&sB[tl][s4 * 4];
      h[s4*4+0] = fmaf(h[s4*4+0], decay, u * b4.x);
      h[s4*4+1] = fmaf(h[s4*4+1], decay, u * b4.y);
      h[s4*4+2] = fmaf(h[s4*4+2], decay, u * b4.z);
      h[s4*4+3] = fmaf(h[s4*4+3], decay, u * b4.w);
    }
    cp *= decay;
  }
#pragma unroll
  for (int s = 0; s < DST; ++s)
    hend[(((size_t)(b * GCH + c)) * DST + s) * DM + di] = h[s];
  pend[((size_t)(b * GCH + c)) * DM + di] = cp;
}

// ---------------- scan phase B (in place: hend -> Hinit at chunk start) ----------------
__global__ __launch_bounds__(256) void scan_b_kernel(
    const float* __restrict__ pend, float* __restrict__ hboth) {
  int blk = blockIdx.x;
  int dblk = blk & 3, s = (blk >> 2) & 15, b = blk >> 6;
  int di = dblk * 256 + threadIdx.x;
  float H = 0.0f;
  for (int c = 0; c < GCH; ++c) {
    size_t hidx = (((size_t)(b * GCH + c)) * DST + s) * DM + di;
    float e = hboth[hidx];
    hboth[hidx] = H;
    float P = pend[((size_t)(b * GCH + c)) * DM + di];
    H = e + P * H;
  }
}

// ---------------- scan pass 2: recompute with true Hinit; y + D-skip + gate -> yH/yL ----------------
__global__ __launch_bounds__(256) void scan_pass2(
    const float* __restrict__ dt, const u16* __restrict__ xsh,
    const u16* __restrict__ xsl, const float* __restrict__ Bm,
    const float* __restrict__ Cm, const float* __restrict__ logA,
    const float* __restrict__ Hinit, const float* __restrict__ Dp,
    const float* __restrict__ zbuf,
    u16* __restrict__ yh, u16* __restrict__ yl) {
  int blk = blockIdx.x;
  int dblk = blk & 3, c = (blk >> 2) & 31, b = blk >> 7;
  int di = dblk * 256 + threadIdx.x;
  __shared__ float sB[LCH][DST];
  __shared__ float sC[LCH][DST];
  {
    int tl = threadIdx.x >> 2, sq = (threadIdx.x & 3) * 4;
    size_t base = ((size_t)(b * TSEQ + c * LCH + tl)) * DST + sq;
    *(float4*)&sB[tl][sq] = *(const float4*)&Bm[base];
    *(float4*)&sC[tl][sq] = *(const float4*)&Cm[base];
  }
  __syncthreads();
  float A_di = -expf(logA[di]);
  float Dv = Dp[di];
  float h[DST];
  size_t hbase = ((size_t)(b * GCH + c)) * DST * DM + di;
#pragma unroll
  for (int s = 0; s < DST; ++s) h[s] = Hinit[hbase + (size_t)s * DM];
  for (int tl = 0; tl < LCH; ++tl) {
    size_t idx = ((size_t)(b * TSEQ + c * LCH + tl)) * DM + di;
    float dtv = dt[idx];
    float xv  = u2f(xsh[idx]) + u2f(xsl[idx]);
    float decay = expf(fminf(dtv * A_di, 0.0f));
    float u = dtv * xv;
    float y = 0.0f;
#pragma unroll
    for (int s4 = 0; s4 < 4; ++s4) {
      float4 b4 = *(const float4*)&sB[tl][s4 * 4];
      float4 c4 = *(const float4*)&sC[tl][s4 * 4];
      h[s4*4+0] = fmaf(h[s4*4+0], decay, u * b4.x); y = fmaf(h[s4*4+0], c4.x, y);
      h[s4*4+1] = fmaf(h[s4*4+1], decay, u * b4.y); y = fmaf(h[s4*4+1], c4.y, y);
      h[s4*4+2] = fmaf(h[s4*4+2], decay, u * b4.z); y = fmaf(h[s4*4+2], c4.z, y);
      h[s4*4+3] = fmaf(h[s4*4+3], decay, u * b4.w); y = fmaf(h[s4*4+3], c4.w, y);
    }
    y = fmaf(xv, Dv, y);
    y *= silu_f(zbuf[idx]);
    u16 hh, ll;
    split1(y, hh, ll);
    yh[idx] = hh;
    yl[idx] = ll;
  }
}

// ---------------- launch ----------------
extern "C" void kernel_launch(void* const* d_in, const int* in_sizes, int n_in,
                              void* d_out, int out_size, void* d_ws, size_t ws_size,
                              hipStream_t stream) {
  const float* x      = (const float*)d_in[0];
  const float* ln_g   = (const float*)d_in[1];
  const float* ln_b   = (const float*)d_in[2];
  const float* W_in   = (const float*)d_in[3];
  const float* conv_w = (const float*)d_in[4];
  const float* conv_b = (const float*)d_in[5];
  const float* dt_w   = (const float*)d_in[6];
  const float* dt_b   = (const float*)d_in[7];
  const float* B_w    = (const float*)d_in[8];
  const float* C_w    = (const float*)d_in[9];
  const float* log_A  = (const float*)d_in[10];
  const float* D_par  = (const float*)d_in[11];
  const float* W_out  = (const float*)d_in[12];
  float* out = (float*)d_out;

  float* ws = (float*)d_ws;
  const size_t NE = (size_t)ROWS * DM;  // 4M elements
  float* bufX  = ws;             // x_ssm pre-conv; after conv reused for Bm/Cm/hend/woutT
  float* bufZ  = bufX + NE;      // z half
  float* bufW  = bufZ + NE;      // early: WinT + dt|B|C weights (12.5 MB); after step 4: pend
  float* bufY  = bufW + NE;      // yH/yL (exactly 16 MB)
  u16*   actH  = (u16*)(bufY + NE);   // xn hi -> xs hi
  u16*   actL  = actH + NE;
  float* bufDT = (float*)(actH + 2 * NE);  // dt
  // y hi/lo fill bufY exactly
  u16*   yH    = (u16*)bufY;
  u16*   yL    = yH + NE;
  // pend lives in bufW (weights dead after step 4; pend written step 5)  [R7 bug: was past bufY, clobbered actH]
  float* bufPe = bufW;                     // [2*32*1024] = 256 KB
  // weights (early phase) aliased into bufW, AFTER the pend slot region is fine too,
  // but keep original layout: winT/dtbc start at bufW; they are dead before pend is written.
  u16* winTh  = (u16*)bufW;
  u16* winTl  = winTh + (size_t)2 * DM * DM;
  u16* dtbcTh = winTl + (size_t)2 * DM * DM;
  u16* dtbcTl = dtbcTh + (size_t)NDTBC * DM;
  // aliases into bufX (valid after conv)
  float* bufBm = bufX;
  float* bufCm = bufBm + (size_t)ROWS * DST;
  float* bufHe = bufCm + (size_t)ROWS * DST;
  u16* woutTh  = (u16*)(bufHe + (size_t)NB * GCH * DST * DM);
  u16* woutTl  = woutTh + (size_t)DM * DM;

  // 0. weight prep: W_in transpose; combined dt|B|C transpose (rows 0..1023 dt, 1024..1151 B/C/pad)
  wsplit_t<<<dim3(2 * DM / 32, DM / 32), 256, 0, stream>>>(W_in, winTh, winTl, DM, 2 * DM);
  wsplit_t<<<dim3(DM / 32, DM / 32), 256, 0, stream>>>(dt_w, dtbcTh, dtbcTl, DM, DM);
  bc_prep<<<NDTBC - DM, 256, 0, stream>>>(B_w, C_w, dtbcTh, dtbcTl);
  // 1. LayerNorm -> xn hi/lo
  ln_kernel<<<ROWS, 256, 0, stream>>>(x, ln_g, ln_b, actH, actL);
  // 2. xz GEMM, split epilogue -> bufX (x half), bufZ (z half)
  gemm_mfma<3><<<dim3(2 * DM / 64, ROWS / 128), 256, 0, stream>>>(
      actH, actL, winTh, winTl, bufX, ROWS, 2 * DM, DM, nullptr, nullptr, bufZ, nullptr);
  // 3. conv + silu -> xs hi/lo (overwrites xn)
  conv_silu_kernel<<<ROWS, 256, 0, stream>>>(bufX, conv_w, conv_b, actH, actL);
  // 3b. W_out transpose (bufX region now free)
  wsplit_t<<<dim3(DM / 32, DM / 32), 256, 0, stream>>>(W_out, woutTh, woutTl, DM, DM);
  // 4. fused dt+B+C GEMM: softplus(dt)+Bm+Cm in one pass
  gemm_mfma<4><<<dim3(NDTBC / 64, ROWS / 128), 256, 0, stream>>>(
      actH, actL, dtbcTh, dtbcTl, bufDT, ROWS, NDTBC, DM, dt_b, nullptr, bufBm, bufCm);
  // 5. scan pass 1: chunk-end states + chunk decay products (pend -> bufW, weights now dead)
  scan_pass1<<<NB * GCH * 4, 256, 0, stream>>>(bufDT, actH, actL, bufBm,
                                               log_A, bufHe, bufPe);
  // 6. combine chunk boundaries (hend -> Hinit in place)
  scan_b_kernel<<<NB * DST * 4, 256, 0, stream>>>(bufPe, bufHe);
  // 7. scan pass 2: exact recompute, y + D-skip + gate -> yH/yL
  scan_pass2<<<NB * GCH * 4, 256, 0, stream>>>(bufDT, actH, actL, bufBm, bufCm,
                                               log_A, bufHe, D_par, bufZ, yH, yL);
  // 8. out = x + y @ W_out
  gemm_mfma<2><<<dim3(DM / 64, ROWS / 128), 256, 0, stream>>>(
      yH, yL, woutTh, woutTl, out, ROWS, DM, DM, nullptr, x, nullptr, nullptr);
}

// Round 9
// 321.993 us; speedup vs baseline: 1.1073x; 1.0885x over previous
//
#include <hip/hip_runtime.h>
#include <cstddef>

#define TSEQ 2048
#define NB   2
#define DM   1024          // D_MODEL == DI
#define DST  16            // D_STATE
#define ROWS (NB*TSEQ)     // 4096
#define GCH  64            // scan chunks
#define LCH  32            // chunk length (GCH*LCH == TSEQ)
#define NDTBC 1088         // dt(1024) + B(16) + C(16) + pad(32)

typedef float  f32x4  __attribute__((ext_vector_type(4)));
typedef short  bf16x8 __attribute__((ext_vector_type(8)));
typedef unsigned short us4 __attribute__((ext_vector_type(4)));
typedef unsigned short u16;

// ---------------- helpers ----------------
__device__ __forceinline__ float u2f(unsigned short u) {
  return __uint_as_float(((unsigned)u) << 16);
}
__device__ __forceinline__ unsigned short bf16_rn(float x) {
  unsigned u = __float_as_uint(x);
  u += 0x7fff + ((u >> 16) & 1);
  return (unsigned short)(u >> 16);
}
__device__ __forceinline__ void split1(float x, u16& h, u16& l) {
  h = bf16_rn(x);
  l = bf16_rn(x - u2f(h));
}
__device__ __forceinline__ void split4(const float4& v, us4& h, us4& l) {
  u16 h0, h1, h2, h3, l0, l1, l2, l3;
  split1(v.x, h0, l0); split1(v.y, h1, l1);
  split1(v.z, h2, l2); split1(v.w, h3, l3);
  h = (us4){h0, h1, h2, h3};
  l = (us4){l0, l1, l2, l3};
}
__device__ __forceinline__ float softplus_f(float x) {
  return fmaxf(x, 0.0f) + log1pf(expf(-fabsf(x)));
}
__device__ __forceinline__ float silu_f(float x) {
  return x / (1.0f + expf(-x));
}
__device__ __forceinline__ void async16(const void* g, void* l) {
  __builtin_amdgcn_global_load_lds(
      (const __attribute__((address_space(1))) unsigned int*)g,
      (__attribute__((address_space(3))) unsigned int*)l, 16, 0, 0);
}
__device__ __forceinline__ float block_reduce_sum(float v, float* smem) {
#pragma unroll
  for (int off = 32; off > 0; off >>= 1) v += __shfl_down(v, off);
  int wid = threadIdx.x >> 6, lane = threadIdx.x & 63;
  if (lane == 0) smem[wid] = v;
  __syncthreads();
  float r = (smem[0] + smem[1]) + (smem[2] + smem[3]);
  __syncthreads();
  return r;
}

// ---------------- weight transpose + bf16 split: W[K][N] -> T[N][K] hi/lo ----------------
__global__ __launch_bounds__(256) void wsplit_t(const float* __restrict__ W,
    u16* __restrict__ Th, u16* __restrict__ Tl, int K, int N) {
  __shared__ float t[32][33];
  int k0 = blockIdx.y * 32, n0 = blockIdx.x * 32;
  int r = threadIdx.x >> 3, cq = (threadIdx.x & 7) * 4;
  float4 v = *(const float4*)&W[(size_t)(k0 + r) * N + n0 + cq];
  t[r][cq + 0] = v.x; t[r][cq + 1] = v.y; t[r][cq + 2] = v.z; t[r][cq + 3] = v.w;
  __syncthreads();
  int n = threadIdx.x >> 3, kq = (threadIdx.x & 7) * 4;
  float4 w4;
  w4.x = t[kq + 0][n]; w4.y = t[kq + 1][n]; w4.z = t[kq + 2][n]; w4.w = t[kq + 3][n];
  us4 h, l;
  split4(w4, h, l);
  size_t o = (size_t)(n0 + n) * K + k0 + kq;
  *(us4*)&Th[o] = h;
  *(us4*)&Tl[o] = l;
}

// ---------------- B/C weight rows (1024..NDTBC-1) of the combined dt|B|C matrix ----------------
__global__ __launch_bounds__(256) void bc_prep(const float* __restrict__ Bw,
    const float* __restrict__ Cw, u16* __restrict__ Th, u16* __restrict__ Tl) {
  int n = DM + blockIdx.x;
  int k = threadIdx.x * 4;
  float4 v = {0.f, 0.f, 0.f, 0.f};
  if (n < DM + DST) {
    int s = n - DM;
    v.x = Bw[(k + 0) * DST + s]; v.y = Bw[(k + 1) * DST + s];
    v.z = Bw[(k + 2) * DST + s]; v.w = Bw[(k + 3) * DST + s];
  } else if (n < DM + 2 * DST) {
    int s = n - DM - DST;
    v.x = Cw[(k + 0) * DST + s]; v.y = Cw[(k + 1) * DST + s];
    v.z = Cw[(k + 2) * DST + s]; v.w = Cw[(k + 3) * DST + s];
  }
  us4 h, l;
  split4(v, h, l);
  size_t o = (size_t)n * DM + k;
  *(us4*)&Th[o] = h;
  *(us4*)&Tl[o] = l;
}

// ---------------- LayerNorm -> bf16 hi/lo ----------------
__global__ __launch_bounds__(256) void ln_kernel(const float* __restrict__ x,
    const float* __restrict__ g, const float* __restrict__ b,
    u16* __restrict__ xh, u16* __restrict__ xl) {
  __shared__ float smem[4];
  int r = blockIdx.x;
  size_t base = (size_t)r * DM + threadIdx.x * 4;
  float4 x4 = *(const float4*)&x[base];
  float s = block_reduce_sum(x4.x + x4.y + x4.z + x4.w, smem);
  float mu = s * (1.0f / DM);
  float d0 = x4.x - mu, d1 = x4.y - mu, d2 = x4.z - mu, d3 = x4.w - mu;
  float v = block_reduce_sum(d0*d0 + d1*d1 + d2*d2 + d3*d3, smem) * (1.0f / DM);
  float inv = rsqrtf(v + 1e-5f);
  float4 g4 = *(const float4*)&g[threadIdx.x * 4];
  float4 b4 = *(const float4*)&b[threadIdx.x * 4];
  float4 o;
  o.x = d0 * inv * g4.x + b4.x;
  o.y = d1 * inv * g4.y + b4.y;
  o.z = d2 * inv * g4.z + b4.z;
  o.w = d3 * inv * g4.w + b4.w;
  us4 h, l;
  split4(o, h, l);
  *(us4*)&xh[base] = h;
  *(us4*)&xl[base] = l;
}

// ---------------- MFMA GEMM (bf16x3 split, BM x 64, BK=32, double-buffered LDS) ----------------
// BM=128 => 256 threads (R5-proven, 3 blocks/CU); BM=256 => 512 threads (16 waves/CU, 2 blocks/CU).
// EPI 2: resid + acc; EPI 3: split cols into C (n<DM) / C2 (n>=DM)
// EPI 4: col<DM -> softplus(acc+bias[col]); DM<=col<DM+16 -> C2 (Bm); next 16 -> C3 (Cm); else discard
template <int EPI, int BM, int NT>
__global__ __launch_bounds__(NT) void gemm_mfma(
    const u16* __restrict__ Ah, const u16* __restrict__ Al,
    const u16* __restrict__ Bh, const u16* __restrict__ Bl,
    float* __restrict__ C, int M, int N, int Kd,
    const float* __restrict__ bias, const float* __restrict__ resid,
    float* __restrict__ C2, float* __restrict__ C3) {
  constexpr int LBUF = BM * 64 + 4096;      // u16 per buffer: Ah BM*32 | Al BM*32 | Bh 2048 | Bl 2048
  constexpr int ROUNDS = (BM * 8 + 512) / NT;
  __shared__ __align__(16) u16 lds[2 * LBUF];
  int tid = threadIdx.x, wave = tid >> 6, lane = tid & 63;
  int m0 = blockIdx.y * BM, n0 = blockIdx.x * 64;
  int wm = (wave >> 1) * 64, wn = (wave & 1) * 32;

  const u16* gptr[ROUNDS];
  int ldst[ROUNDS];
#pragma unroll
  for (int r = 0; r < ROUNDS; ++r) {
    int c = r * NT + tid;
    int kq = c & 3;
    const u16* base;
    int row;
    if (c < BM * 4)            { base = Ah + (size_t)m0 * Kd; row = c >> 2; }
    else if (c < BM * 8)       { base = Al + (size_t)m0 * Kd; row = (c - BM * 4) >> 2; }
    else if (c < BM * 8 + 256) { base = Bh + (size_t)n0 * Kd; row = (c - BM * 8) >> 2; }
    else                       { base = Bl + (size_t)n0 * Kd; row = (c - BM * 8 - 256) >> 2; }
    gptr[r] = base + (size_t)row * Kd + kq * 8;
    ldst[r] = c * 8;
  }

  f32x4 acc[4][2];
#pragma unroll
  for (int i = 0; i < 4; ++i)
#pragma unroll
    for (int j = 0; j < 2; ++j) acc[i][j] = (f32x4){0.f, 0.f, 0.f, 0.f};
  int fr = lane & 15, quad = lane >> 4;

  // prologue: stage k=0 into buffer 0
#pragma unroll
  for (int r = 0; r < ROUNDS; ++r) async16(gptr[r], lds + ldst[r]);

  int nsteps = Kd / 32;
  for (int s = 0; s < nsteps; ++s) {
    int cur = (s & 1) * LBUF;
    __syncthreads();  // drains cur's loads; other-buffer compute overlapped them
    if (s + 1 < nsteps) {
      int ko = (s + 1) * 32;
      int nxt = ((s + 1) & 1) * LBUF;
#pragma unroll
      for (int r = 0; r < ROUNDS; ++r) async16(gptr[r] + ko, lds + nxt + ldst[r]);
    }
    const u16* sAh = lds + cur;
    const u16* sAl = lds + cur + BM * 32;
    const u16* sBh = lds + cur + BM * 64;
    const u16* sBl = lds + cur + BM * 64 + 2048;
    bf16x8 afh[4], afl[4], bfh[2], bfl[2];
#pragma unroll
    for (int t = 0; t < 4; ++t) {
      int ro = (wm + t * 16 + fr) * 32 + quad * 8;
      afh[t] = *(const bf16x8*)&sAh[ro];
      afl[t] = *(const bf16x8*)&sAl[ro];
    }
#pragma unroll
    for (int t = 0; t < 2; ++t) {
      int co = (wn + t * 16 + fr) * 32 + quad * 8;
      bfh[t] = *(const bf16x8*)&sBh[co];
      bfl[t] = *(const bf16x8*)&sBl[co];
    }
#pragma unroll
    for (int mt = 0; mt < 4; ++mt)
#pragma unroll
      for (int nt = 0; nt < 2; ++nt) {
        acc[mt][nt] = __builtin_amdgcn_mfma_f32_16x16x32_bf16(afh[mt], bfh[nt], acc[mt][nt], 0, 0, 0);
        acc[mt][nt] = __builtin_amdgcn_mfma_f32_16x16x32_bf16(afh[mt], bfl[nt], acc[mt][nt], 0, 0, 0);
        acc[mt][nt] = __builtin_amdgcn_mfma_f32_16x16x32_bf16(afl[mt], bfh[nt], acc[mt][nt], 0, 0, 0);
      }
  }

#pragma unroll
  for (int mt = 0; mt < 4; ++mt)
#pragma unroll
    for (int nt = 0; nt < 2; ++nt) {
      int col = n0 + wn + nt * 16 + fr;
#pragma unroll
      for (int r = 0; r < 4; ++r) {
        int row = m0 + wm + mt * 16 + quad * 4 + r;
        float v = acc[mt][nt][r];
        if (EPI == 2) {
          v += resid[(size_t)row * N + col];
          C[(size_t)row * N + col] = v;
        } else if (EPI == 3) {
          if (col < DM) C[(size_t)row * DM + col] = v;
          else          C2[(size_t)row * DM + col - DM] = v;
        } else if (EPI == 4) {
          if (col < DM) {
            C[(size_t)row * DM + col] = softplus_f(v + bias[col]);
          } else if (col < DM + DST) {
            C2[(size_t)row * DST + col - DM] = v;
          } else if (col < DM + 2 * DST) {
            C3[(size_t)row * DST + col - DM - DST] = v;
          }
        } else {
          C[(size_t)row * N + col] = v;
        }
      }
    }
}

// ---------------- causal depthwise conv (K=4) + SiLU -> xs hi/lo ----------------
__global__ __launch_bounds__(256) void conv_silu_kernel(
    const float* __restrict__ xin, const float* __restrict__ w,
    const float* __restrict__ cb, u16* __restrict__ xsh, u16* __restrict__ xsl) {
  int r = blockIdx.x;
  int b = r >> 11, t = r & 2047;
  int d = threadIdx.x * 4;
  float4 w0 = *(const float4*)&w[(d + 0) * 4];
  float4 w1 = *(const float4*)&w[(d + 1) * 4];
  float4 w2 = *(const float4*)&w[(d + 2) * 4];
  float4 w3 = *(const float4*)&w[(d + 3) * 4];
  float4 s = *(const float4*)&cb[d];
#pragma unroll
  for (int k = 0; k < 4; ++k) {
    int ts = t + k - 3;
    if (ts >= 0) {
      float4 xv = *(const float4*)&xin[((size_t)(b * TSEQ + ts)) * DM + d];
      s.x = fmaf(xv.x, (&w0.x)[k], s.x);
      s.y = fmaf(xv.y, (&w1.x)[k], s.y);
      s.z = fmaf(xv.z, (&w2.x)[k], s.z);
      s.w = fmaf(xv.w, (&w3.x)[k], s.w);
    }
  }
  float4 o;
  o.x = silu_f(s.x); o.y = silu_f(s.y); o.z = silu_f(s.z); o.w = silu_f(s.w);
  us4 h, l;
  split4(o, h, l);
  size_t base = (size_t)r * DM + d;
  *(us4*)&xsh[base] = h;
  *(us4*)&xsl[base] = l;
}

// ---------------- scan pass 1: chunk-end state + chunk decay product ----------------
__global__ __launch_bounds__(256) void scan_pass1(
    const float* __restrict__ dt, const u16* __restrict__ xsh,
    const u16* __restrict__ xsl, const float* __restrict__ Bm,
    const float* __restrict__ logA,
    float* __restrict__ hend, float* __restrict__ pend) {
  int blk = blockIdx.x;
  int dblk = blk & 3, c = (blk >> 2) & (GCH - 1), b = blk >> 8;
  int di = dblk * 256 + threadIdx.x;
  __shared__ float sB[LCH][DST];
  if (threadIdx.x < LCH * 4) {
    int tl = threadIdx.x >> 2, sq = (threadIdx.x & 3) * 4;
    size_t base = ((size_t)(b * TSEQ + c * LCH + tl)) * DST + sq;
    *(float4*)&sB[tl][sq] = *(const float4*)&Bm[base];
  }
  __syncthreads();
  float A_di = -expf(logA[di]);
  float h[DST];
#pragma unroll
  for (int s = 0; s < DST; ++s) h[s] = 0.0f;
  float cp = 1.0f;
#pragma unroll 4
  for (int tl = 0; tl < LCH; ++tl) {
    size_t idx = ((size_t)(b * TSEQ + c * LCH + tl)) * DM + di;
    float dtv = dt[idx];
    float xv  = u2f(xsh[idx]) + u2f(xsl[idx]);
    float decay = expf(fminf(dtv * A_di, 0.0f));
    float u = dtv * xv;
#pragma unroll
    for (int s4 = 0; s4 < 4; ++s4) {
      float4 b4 = *(const float4*)&sB[tl][s4 * 4];
      h[s4*4+0] = fmaf(h[s4*4+0], decay, u * b4.x);
      h[s4*4+1] = fmaf(h[s4*4+1], decay, u * b4.y);
      h[s4*4+2] = fmaf(h[s4*4+2], decay, u * b4.z);
      h[s4*4+3] = fmaf(h[s4*4+3], decay, u * b4.w);
    }
    cp *= decay;
  }
#pragma unroll
  for (int s = 0; s < DST; ++s)
    hend[(((size_t)(b * GCH + c)) * DST + s) * DM + di] = h[s];
  pend[((size_t)(b * GCH + c)) * DM + di] = cp;
}

// ---------------- scan phase B (in place: hend -> Hinit at chunk start) ----------------
__global__ __launch_bounds__(256) void scan_b_kernel(
    const float* __restrict__ pend, float* __restrict__ hboth) {
  int blk = blockIdx.x;
  int dblk = blk & 3, s = (blk >> 2) & 15, b = blk >> 6;
  int di = dblk * 256 + threadIdx.x;
  float H = 0.0f;
  for (int c = 0; c < GCH; ++c) {
    size_t hidx = (((size_t)(b * GCH + c)) * DST + s) * DM + di;
    float e = hboth[hidx];
    hboth[hidx] = H;
    float P = pend[((size_t)(b * GCH + c)) * DM + di];
    H = e + P * H;
  }
}

// ---------------- scan pass 2: recompute with true Hinit; y + D-skip + gate -> yH/yL ----------------
__global__ __launch_bounds__(256) void scan_pass2(
    const float* __restrict__ dt, const u16* __restrict__ xsh,
    const u16* __restrict__ xsl, const float* __restrict__ Bm,
    const float* __restrict__ Cm, const float* __restrict__ logA,
    const float* __restrict__ Hinit, const float* __restrict__ Dp,
    const float* __restrict__ zbuf,
    u16* __restrict__ yh, u16* __restrict__ yl) {
  int blk = blockIdx.x;
  int dblk = blk & 3, c = (blk >> 2) & (GCH - 1), b = blk >> 8;
  int di = dblk * 256 + threadIdx.x;
  __shared__ float sB[LCH][DST];
  __shared__ float sC[LCH][DST];
  if (threadIdx.x < LCH * 4) {
    int tl = threadIdx.x >> 2, sq = (threadIdx.x & 3) * 4;
    size_t base = ((size_t)(b * TSEQ + c * LCH + tl)) * DST + sq;
    *(float4*)&sB[tl][sq] = *(const float4*)&Bm[base];
  } else if (threadIdx.x < LCH * 8) {
    int t2 = threadIdx.x - LCH * 4;
    int tl = t2 >> 2, sq = (t2 & 3) * 4;
    size_t base = ((size_t)(b * TSEQ + c * LCH + tl)) * DST + sq;
    *(float4*)&sC[tl][sq] = *(const float4*)&Cm[base];
  }
  __syncthreads();
  float A_di = -expf(logA[di]);
  float Dv = Dp[di];
  float h[DST];
  size_t hbase = ((size_t)(b * GCH + c)) * DST * DM + di;
#pragma unroll
  for (int s = 0; s < DST; ++s) h[s] = Hinit[hbase + (size_t)s * DM];
#pragma unroll 4
  for (int tl = 0; tl < LCH; ++tl) {
    size_t idx = ((size_t)(b * TSEQ + c * LCH + tl)) * DM + di;
    float dtv = dt[idx];
    float xv  = u2f(xsh[idx]) + u2f(xsl[idx]);
    float decay = expf(fminf(dtv * A_di, 0.0f));
    float u = dtv * xv;
    float y0 = 0.f, y1 = 0.f, y2 = 0.f, y3 = 0.f;
    {
      float4 b4 = *(const float4*)&sB[tl][0];
      float4 c4 = *(const float4*)&sC[tl][0];
      h[0] = fmaf(h[0], decay, u * b4.x); y0 = fmaf(h[0], c4.x, y0);
      h[1] = fmaf(h[1], decay, u * b4.y); y1 = fmaf(h[1], c4.y, y1);
      h[2] = fmaf(h[2], decay, u * b4.z); y2 = fmaf(h[2], c4.z, y2);
      h[3] = fmaf(h[3], decay, u * b4.w); y3 = fmaf(h[3], c4.w, y3);
    }
    {
      float4 b4 = *(const float4*)&sB[tl][4];
      float4 c4 = *(const float4*)&sC[tl][4];
      h[4] = fmaf(h[4], decay, u * b4.x); y0 = fmaf(h[4], c4.x, y0);
      h[5] = fmaf(h[5], decay, u * b4.y); y1 = fmaf(h[5], c4.y, y1);
      h[6] = fmaf(h[6], decay, u * b4.z); y2 = fmaf(h[6], c4.z, y2);
      h[7] = fmaf(h[7], decay, u * b4.w); y3 = fmaf(h[7], c4.w, y3);
    }
    {
      float4 b4 = *(const float4*)&sB[tl][8];
      float4 c4 = *(const float4*)&sC[tl][8];
      h[8]  = fmaf(h[8],  decay, u * b4.x); y0 = fmaf(h[8],  c4.x, y0);
      h[9]  = fmaf(h[9],  decay, u * b4.y); y1 = fmaf(h[9],  c4.y, y1);
      h[10] = fmaf(h[10], decay, u * b4.z); y2 = fmaf(h[10], c4.z, y2);
      h[11] = fmaf(h[11], decay, u * b4.w); y3 = fmaf(h[11], c4.w, y3);
    }
    {
      float4 b4 = *(const float4*)&sB[tl][12];
      float4 c4 = *(const float4*)&sC[tl][12];
      h[12] = fmaf(h[12], decay, u * b4.x); y0 = fmaf(h[12], c4.x, y0);
      h[13] = fmaf(h[13], decay, u * b4.y); y1 = fmaf(h[13], c4.y, y1);
      h[14] = fmaf(h[14], decay, u * b4.z); y2 = fmaf(h[14], c4.z, y2);
      h[15] = fmaf(h[15], decay, u * b4.w); y3 = fmaf(h[15], c4.w, y3);
    }
    float y = (y0 + y1) + (y2 + y3);
    y = fmaf(xv, Dv, y);
    y *= silu_f(zbuf[idx]);
    u16 hh, ll;
    split1(y, hh, ll);
    yh[idx] = hh;
    yl[idx] = ll;
  }
}

// ---------------- launch ----------------
extern "C" void kernel_launch(void* const* d_in, const int* in_sizes, int n_in,
                              void* d_out, int out_size, void* d_ws, size_t ws_size,
                              hipStream_t stream) {
  const float* x      = (const float*)d_in[0];
  const float* ln_g   = (const float*)d_in[1];
  const float* ln_b   = (const float*)d_in[2];
  const float* W_in   = (const float*)d_in[3];
  const float* conv_w = (const float*)d_in[4];
  const float* conv_b = (const float*)d_in[5];
  const float* dt_w   = (const float*)d_in[6];
  const float* dt_b   = (const float*)d_in[7];
  const float* B_w    = (const float*)d_in[8];
  const float* C_w    = (const float*)d_in[9];
  const float* log_A  = (const float*)d_in[10];
  const float* D_par  = (const float*)d_in[11];
  const float* W_out  = (const float*)d_in[12];
  float* out = (float*)d_out;

  float* ws = (float*)d_ws;
  const size_t NE = (size_t)ROWS * DM;  // 4M elements
  float* bufX  = ws;             // x_ssm pre-conv; after conv: Bm/Cm/hend/woutT
  float* bufZ  = bufX + NE;      // z half
  float* bufW  = bufZ + NE;      // early: WinT + dt|B|C weights; after step 4: pend
  float* bufY  = bufW + NE;      // yH/yL (exactly 16 MB)
  u16*   actH  = (u16*)(bufY + NE);   // xn hi -> xs hi
  u16*   actL  = actH + NE;
  float* bufDT = (float*)(actH + 2 * NE);  // dt
  u16*   yH    = (u16*)bufY;
  u16*   yL    = yH + NE;
  float* bufPe = bufW;                     // pend [2*64*1024] = 512 KB (weights dead)
  u16* winTh  = (u16*)bufW;
  u16* winTl  = winTh + (size_t)2 * DM * DM;
  u16* dtbcTh = winTl + (size_t)2 * DM * DM;
  u16* dtbcTl = dtbcTh + (size_t)NDTBC * DM;
  // aliases into bufX (valid after conv): 256K + 256K + 8 MB + 4 MB = 12.5 MB
  float* bufBm = bufX;
  float* bufCm = bufBm + (size_t)ROWS * DST;
  float* bufHe = bufCm + (size_t)ROWS * DST;
  u16* woutTh  = (u16*)(bufHe + (size_t)NB * GCH * DST * DM);
  u16* woutTl  = woutTh + (size_t)DM * DM;

  // 0. weight prep
  wsplit_t<<<dim3(2 * DM / 32, DM / 32), 256, 0, stream>>>(W_in, winTh, winTl, DM, 2 * DM);
  wsplit_t<<<dim3(DM / 32, DM / 32), 256, 0, stream>>>(dt_w, dtbcTh, dtbcTl, DM, DM);
  bc_prep<<<NDTBC - DM, 256, 0, stream>>>(B_w, C_w, dtbcTh, dtbcTl);
  // 1. LayerNorm -> xn hi/lo
  ln_kernel<<<ROWS, 256, 0, stream>>>(x, ln_g, ln_b, actH, actL);
  // 2. xz GEMM (BM=256, 512 threads), split epilogue -> bufX (x half), bufZ (z half)
  gemm_mfma<3, 256, 512><<<dim3(2 * DM / 64, ROWS / 256), 512, 0, stream>>>(
      actH, actL, winTh, winTl, bufX, ROWS, 2 * DM, DM, nullptr, nullptr, bufZ, nullptr);
  // 3. conv + silu -> xs hi/lo (overwrites xn)
  conv_silu_kernel<<<ROWS, 256, 0, stream>>>(bufX, conv_w, conv_b, actH, actL);
  // 3b. W_out transpose (bufX region now free)
  wsplit_t<<<dim3(DM / 32, DM / 32), 256, 0, stream>>>(W_out, woutTh, woutTl, DM, DM);
  // 4. fused dt+B+C GEMM (BM=128): softplus(dt)+Bm+Cm in one pass
  gemm_mfma<4, 128, 256><<<dim3(NDTBC / 64, ROWS / 128), 256, 0, stream>>>(
      actH, actL, dtbcTh, dtbcTl, bufDT, ROWS, NDTBC, DM, dt_b, nullptr, bufBm, bufCm);
  // 5. scan pass 1: chunk-end states + chunk decay products
  scan_pass1<<<NB * GCH * 4, 256, 0, stream>>>(bufDT, actH, actL, bufBm,
                                               log_A, bufHe, bufPe);
  // 6. combine chunk boundaries (hend -> Hinit in place)
  scan_b_kernel<<<NB * DST * 4, 256, 0, stream>>>(bufPe, bufHe);
  // 7. scan pass 2: exact recompute, y + D-skip + gate -> yH/yL
  scan_pass2<<<NB * GCH * 4, 256, 0, stream>>>(bufDT, actH, actL, bufBm, bufCm,
                                               log_A, bufHe, D_par, bufZ, yH, yL);
  // 8. out = x + y @ W_out (BM=128)
  gemm_mfma<2, 128, 256><<<dim3(DM / 64, ROWS / 128), 256, 0, stream>>>(
      yH, yL, woutTh, woutTl, out, ROWS, DM, DM, nullptr, x, nullptr, nullptr);
}